// Round 1
// baseline (201.426 us; speedup 1.0000x reference)
//
#include <hip/hip_runtime.h>
#include <hip/hip_bf16.h>

// Causal attention: B=2, H=12, S=2048, D=64, fp32 in/out.
// Reference's mask-direction logic resolves to plain causal (mask = tril,
// flip=False) -> mask input (d_in[3]) ignored, causality hardcoded.
//
// Flash-attention: block = 4 waves = 64 Q rows of one head; K/V tiles 64x64
// staged fp32->bf16 in LDS; QK^T and PV via mfma_f32_16x16x32_bf16; P goes
// C-layout -> A-layout through a per-wave LDS round trip (m120 pattern).

#define SEQ 2048
#define DH 64
#define NHEADS 24   // B*H
#define BM 64
#define BN 64
#define LDK 72      // padded LDS row length (bf16 elements): 144 B, breaks 32-bank stride

typedef float f32x4 __attribute__((ext_vector_type(4)));
typedef __bf16 bf16x8 __attribute__((ext_vector_type(8)));

__global__ __launch_bounds__(256, 2)
void fa_causal_kernel(const float* __restrict__ q, const float* __restrict__ k,
                      const float* __restrict__ v, float* __restrict__ out)
{
    // heavy q-tiles (more k iterations) get low blockIdx -> launch first
    const int mt = 31 - (blockIdx.x & 31);
    const int bh = blockIdx.x >> 5;
    const int tid = threadIdx.x;
    const int w   = tid >> 6;       // wave 0..3
    const int lane = tid & 63;
    const int g   = lane >> 4;      // quad 0..3
    const int li  = lane & 15;
    const int m0  = mt * BM;

    __shared__ __bf16 Ks[BN][LDK];        // Ks[kv][d]
    __shared__ __bf16 Vs[DH][LDK];        // transposed: Vs[d][kv]
    __shared__ __bf16 Ps[4][16][LDK];     // per-wave P tile [m][kv]

    const size_t head_off = (size_t)bh * SEQ * DH;
    const float* qh = q + head_off;
    const float* kh = k + head_off;
    const float* vh = v + head_off;
    float* oh = out + head_off;

    // ---- Q fragments in registers: rows m0 + w*16 + li, A-layout ----
    const int qrow = m0 + w * 16 + li;
    bf16x8 qf[2];
    {
        const float* qp = qh + (size_t)qrow * DH + g * 8;
        #pragma unroll
        for (int c = 0; c < 2; ++c) {
            const float* p = qp + c * 32;
            #pragma unroll
            for (int jj = 0; jj < 8; ++jj) qf[c][jj] = (__bf16)p[jj];
        }
    }

    f32x4 acc[4] = {};                    // O accumulator, C-layout, 4 n-tiles over D
    float mrow[4], lrow[4];
    #pragma unroll
    for (int r = 0; r < 4; ++r) { mrow[r] = -1e30f; lrow[r] = 0.0f; }

    const float scale = 0.125f;           // 1/sqrt(64)

    // staging indices: 256 threads cover a 64x64 fp32 tile, 16 elems each
    const int srow = tid >> 2;            // 0..63
    const int scol = (tid & 3) * 16;      // 0,16,32,48

    for (int jt = 0; jt <= mt; ++jt) {
        const int kv0 = jt * BN;
        __syncthreads();  // prior iteration's PV reads of Ks/Vs done
        {
            // K tile -> LDS (bf16, row-major)
            const float* kp = kh + (size_t)(kv0 + srow) * DH + scol;
            __bf16 tmp[16];
            #pragma unroll
            for (int jj = 0; jj < 16; ++jj) tmp[jj] = (__bf16)kp[jj];
            *(bf16x8*)&Ks[srow][scol]     = *(bf16x8*)&tmp[0];
            *(bf16x8*)&Ks[srow][scol + 8] = *(bf16x8*)&tmp[8];
            // V tile -> LDS transposed
            const float* vp = vh + (size_t)(kv0 + srow) * DH + scol;
            #pragma unroll
            for (int jj = 0; jj < 16; ++jj) Vs[scol + jj][srow] = (__bf16)vp[jj];
        }
        __syncthreads();

        // ---- S = Q K^T (16 x 64 per wave) ----
        float s[4][4];
        #pragma unroll
        for (int t = 0; t < 4; ++t) {
            f32x4 sa = {};
            #pragma unroll
            for (int c = 0; c < 2; ++c) {
                bf16x8 kf = *(const bf16x8*)&Ks[t * 16 + li][c * 32 + g * 8];
                sa = __builtin_amdgcn_mfma_f32_16x16x32_bf16(qf[c], kf, sa, 0, 0, 0);
            }
            #pragma unroll
            for (int r = 0; r < 4; ++r) s[t][r] = sa[r] * scale;
        }

        // causal mask: only the diagonal tile needs per-element masking
        if (jt == mt) {
            #pragma unroll
            for (int t = 0; t < 4; ++t) {
                const int col = kv0 + t * 16 + li;
                #pragma unroll
                for (int r = 0; r < 4; ++r) {
                    const int row = m0 + w * 16 + g * 4 + r;
                    if (col > row) s[t][r] = -1e30f;
                }
            }
        }

        // ---- online softmax (rows live across lanes with same quad g) ----
        #pragma unroll
        for (int r = 0; r < 4; ++r) {
            float mx = fmaxf(fmaxf(s[0][r], s[1][r]), fmaxf(s[2][r], s[3][r]));
            #pragma unroll
            for (int off = 1; off < 16; off <<= 1)
                mx = fmaxf(mx, __shfl_xor(mx, off, 64));
            const float mnew = fmaxf(mrow[r], mx);
            const float alpha = __expf(mrow[r] - mnew);
            mrow[r] = mnew;
            float ps = 0.0f;
            #pragma unroll
            for (int t = 0; t < 4; ++t) {
                const float p = __expf(s[t][r] - mnew);
                s[t][r] = p;
                ps += p;
            }
            #pragma unroll
            for (int off = 1; off < 16; off <<= 1)
                ps += __shfl_xor(ps, off, 64);
            lrow[r] = lrow[r] * alpha + ps;
            #pragma unroll
            for (int t = 0; t < 4; ++t) acc[t][r] *= alpha;
        }

        // ---- P: C-layout -> LDS -> A-layout ----
        #pragma unroll
        for (int t = 0; t < 4; ++t)
            #pragma unroll
            for (int r = 0; r < 4; ++r)
                Ps[w][g * 4 + r][t * 16 + li] = (__bf16)s[t][r];
        __syncthreads();  // orders wave-local Ps write->read; cheap & safe for round 0

        // ---- O += P V ----
        #pragma unroll
        for (int c = 0; c < 2; ++c) {
            bf16x8 pf = *(const bf16x8*)&Ps[w][li][c * 32 + g * 8];
            #pragma unroll
            for (int t = 0; t < 4; ++t) {
                bf16x8 vf = *(const bf16x8*)&Vs[t * 16 + li][c * 32 + g * 8];
                acc[t] = __builtin_amdgcn_mfma_f32_16x16x32_bf16(pf, vf, acc[t], 0, 0, 0);
            }
        }
    }

    // ---- epilogue: O = acc / l ----
    #pragma unroll
    for (int r = 0; r < 4; ++r) {
        const int row = m0 + w * 16 + g * 4 + r;
        const float inv = 1.0f / lrow[r];
        float* op = oh + (size_t)row * DH + li;
        #pragma unroll
        for (int t = 0; t < 4; ++t) op[t * 16] = acc[t][r] * inv;
    }
}

extern "C" void kernel_launch(void* const* d_in, const int* in_sizes, int n_in,
                              void* d_out, int out_size, void* d_ws, size_t ws_size,
                              hipStream_t stream) {
    (void)in_sizes; (void)n_in; (void)d_ws; (void)ws_size; (void)out_size;
    const float* q = (const float*)d_in[0];
    const float* k = (const float*)d_in[1];
    const float* v = (const float*)d_in[2];
    // d_in[3] = mask: tril(ones) -> plain causal, hardcoded in kernel
    float* out = (float*)d_out;
    dim3 grid(NHEADS * (SEQ / BM));   // 24 * 32 = 768
    dim3 block(256);
    fa_causal_kernel<<<grid, block, 0, stream>>>(q, k, v, out);
}